// Round 13
// baseline (9479.387 us; speedup 1.0000x reference)
//
#include <hip/hip_runtime.h>

typedef unsigned short u16;
typedef unsigned int u32;
typedef __bf16 bf16x8 __attribute__((ext_vector_type(8)));
typedef float f32x4 __attribute__((ext_vector_type(4)));
typedef u16 u16x8 __attribute__((ext_vector_type(8)));

#define AS1 __attribute__((address_space(1)))
#define AS3 __attribute__((address_space(3)))

constexpr int Bsz = 512;   // batch
constexpr int LATn = 128;  // latent
constexpr int Hn  = 1024;  // hidden
constexpr int G4H = 4096;  // 4*H
constexpr int NBLK = 256;

__device__ __forceinline__ u16 f2bf(float x){
  u32 u = __float_as_uint(x);
  return (u16)((u + 0x7FFFu + ((u >> 16) & 1u)) >> 16);
}
__device__ __forceinline__ float bf2f(u16 h){ return __uint_as_float(((u32)h) << 16); }

__device__ __forceinline__ float sigm(float x){
  float e = __builtin_amdgcn_exp2f(x * -1.44269504088896f);
  return __builtin_amdgcn_rcpf(1.0f + e);
}
__device__ __forceinline__ float tanh_f(float x){
  float e = __builtin_amdgcn_exp2f(x * -2.88539008177793f);
  return __builtin_amdgcn_rcpf(1.0f + e) * 2.0f - 1.0f;
}

__device__ __forceinline__ bf16x8 ld8(const u16* p){
  u16x8 v = *reinterpret_cast<const u16x8*>(p);
  return __builtin_bit_cast(bf16x8, v);
}
// volatile load: bypass L1 so same-XCD L2 (the coherence point) is always consulted
__device__ __forceinline__ bf16x8 vld8(const volatile u16* p){
  u16x8 v = *reinterpret_cast<const volatile u16x8*>(p);
  return __builtin_bit_cast(bf16x8, v);
}

__device__ __forceinline__ void load16_lds(const u16* g, u16* l){
  __builtin_amdgcn_global_load_lds((AS1 void*)(u16*)g, (AS3 void*)l, 16, 0, 0);
}

// ---------------- repack: fold y-feedback into weights, fp32 -> bf16 hi/lo ----------------
// W'[gc][k] = Whh[gc][k] + Wout[k]*Wih[gc];  bias' = b_ih + b_hh + bo*Wih
// 64-col gate packing (all 4 gates of 16 j's contiguous): drow = (jj>>4)*64 + g*16 + (jj&15)
__global__ void repack_kernel(
    const float* __restrict__ Whh, const float* __restrict__ b_ih, const float* __restrict__ b_hh,
    const float* __restrict__ Wih, const float* __restrict__ Wout, const float* __restrict__ bout,
    u16* wp_hi, u16* wp_lo, float* bpack, float* wihpack)
{
  const int idx0 = blockIdx.x * blockDim.x + threadIdx.x;
  const int stride = gridDim.x * blockDim.x;
  const float bo = bout[0];
  for (int i = idx0; i < G4H * Hn; i += stride){
    int row = i >> 10, k = i & 1023;
    int g = row >> 10, jj = row & 1023;
    int drow = (jj >> 4) * 64 + g * 16 + (jj & 15);
    float x = Whh[i] + Wout[k] * Wih[row];
    u16 hi = f2bf(x);
    wp_hi[drow * 1024 + k] = hi;
    wp_lo[drow * 1024 + k] = f2bf(x - bf2f(hi));
  }
  for (int i = idx0; i < G4H; i += stride){
    int g = i >> 10, jj = i & 1023;
    int drow = (jj >> 4) * 64 + g * 16 + (jj & 15);
    bpack[drow] = b_ih[i] + b_hh[i] + bo * Wih[i];
    wihpack[drow] = Wih[i];
  }
}

// ---------------- init: h0, c0, y_init (one block per batch row) ----------------
__global__ __launch_bounds__(256, 1) void init_kernel(
    const float* __restrict__ z,
    const float* __restrict__ Wzh, const float* __restrict__ bzh,
    const float* __restrict__ Wzc, const float* __restrict__ bzc,
    const float* __restrict__ Wout, const float* __restrict__ bout,
    u16* hb_hi, u16* hb_lo, float* cbuf, float* yinit)
{
  __shared__ float zrow[LATn];
  __shared__ float yred[256];
  const int b = blockIdx.x, tid = threadIdx.x;
  if (tid < LATn) zrow[tid] = z[b * LATn + tid];
  __syncthreads();
  float ysum = 0.f;
  #pragma unroll
  for (int jj = 0; jj < 4; ++jj){
    const int j = tid * 4 + jj;
    const float* wh = Wzh + (size_t)j * LATn;
    const float* wc = Wzc + (size_t)j * LATn;
    float sh = bzh[j], sc = bzc[j];
    for (int k = 0; k < LATn; ++k){
      const float zv = zrow[k];
      sh = fmaf(zv, wh[k], sh);
      sc = fmaf(zv, wc[k], sc);
    }
    const float h0 = tanh_f(sh);
    cbuf[(size_t)b * Hn + j] = tanh_f(sc);
    const u16 hi = f2bf(h0);
    hb_hi[(size_t)b * Hn + j] = hi;
    hb_lo[(size_t)b * Hn + j] = f2bf(h0 - bf2f(hi));
    ysum = fmaf(h0, Wout[j], ysum);
  }
  yred[tid] = ysum;
  __syncthreads();
  for (int s = 128; s > 0; s >>= 1){
    if (tid < s) yred[tid] += yred[tid + s];
    __syncthreads();
  }
  if (tid == 0) yinit[b] = yred[0] + bout[0];
}

// ---------------- persistent XCD-local LSTM kernel, 4-deep stream pipeline ----------------
// 256 blocks x 512 threads, 128 KB LDS -> 1 block/CU guaranteed -> 32 blocks/XCD.
// XCD x owns batch rows [x*64, x*64+64): no fences, XCD-local flag barrier.
// W' streamed L3 -> LDS in 4 x 32 KB ring buffers, 3 chunks ahead, raw s_barrier +
// counted vmcnt(16) (stages stay in flight across barriers). h via depth-3 reg ring.
__global__ __launch_bounds__(512, 1) void lstm_xcd(
    const u16* __restrict__ wp_hi, const u16* __restrict__ wp_lo,
    const float* __restrict__ bpack, const float* __restrict__ wihpack,
    const float* __restrict__ Wout, const float* __restrict__ bout,
    const float* __restrict__ yinit,
    u16* __restrict__ hb_hi, u16* __restrict__ hb_lo,
    const float* __restrict__ cbuf, float* __restrict__ ypart,
    float* __restrict__ outp, const int* __restrict__ tlen,
    u32* claim, volatile u32* flags)
{
  __shared__ __align__(16) u16 ldsB[4][2][8192];  // 128 KiB ring: [buf][hi/lo][col*64+sp*8]
  __shared__ int sh_ids[2];

  const int tid = threadIdx.x;
  const int lane = tid & 63, w = tid >> 6;
  const int r = lane & 15, q = lane >> 4;
  const int rowg = w >> 1, jt = w & 1;
  const int T = tlen[0];

  // ---- physical XCD id + slot claim ----
  if (tid == 0){
    const int xcd_ = (int)(__builtin_amdgcn_s_getreg(6164) & 7);  // HW_REG_XCC_ID(20), sz 4
    const int slot_ = (int)atomicAdd(&claim[xcd_ * 16], 1u);
    sh_ids[0] = xcd_; sh_ids[1] = slot_;
  }
  __syncthreads();
  const int xcd = sh_ids[0];
  const int slot = sh_ids[1] & 31;

  const int jcol0 = slot * 128;                 // packed W' col base (128 cols = 32 j)
  const int j = slot * 32 + jt * 16 + r;        // this lane's hidden unit
  const int row0x = xcd * 64;                   // XCD's batch-row base
  const int wrow0 = row0x + rowg * 16;          // wave's A-row base

  volatile u32* myflag = flags + (size_t)(xcd * 32 + slot) * 16;  // 64B padded
  volatile u32* gflag  = flags + (size_t)(xcd * 32) * 16;

  // per-lane constants
  float bias_r[4], wih_r[4];
  #pragma unroll
  for (int nt = 0; nt < 4; ++nt){
    bias_r[nt] = bpack[jcol0 + jt * 64 + nt * 16 + r];
    wih_r[nt]  = wihpack[jcol0 + jt * 64 + nt * 16 + r];
  }
  const float wout_r = Wout[j];
  const float bo = bout[0];

  // c state in registers for all steps: rows q*4+e of this wave, column j
  float creg[4];
  #pragma unroll
  for (int e = 0; e < 4; ++e)
    creg[e] = cbuf[(size_t)(wrow0 + q * 4 + e) * Hn + j];

  const u16* wph = wp_hi + (size_t)jcol0 * 1024;
  const u16* wpl = wp_lo + (size_t)jcol0 * 1024;

  // stage W' chunk c (128 cols x 64 k, hi+lo = 32 KB) into ldsB[c&3]; 4 loads/thread
  auto stage = [&](int c){
    const int buf = c & 3;
    #pragma unroll
    for (int i = 0; i < 2; ++i){
      const int idx = i * 512 + tid;
      const int col = idx >> 3, sp = idx & 7;
      const int sgk = (sp ^ (col & 7)) * 8;     // inverse of read-side swizzle
      const int dst = (i * 512 + w * 64) * 8;   // wave-uniform; HW adds lane*16B
      load16_lds(wph + col * 1024 + c * 64 + sgk, &ldsB[buf][0][dst]);
      load16_lds(wpl + col * 1024 + c * 64 + sgk, &ldsB[buf][1][dst]);
    }
  };

  // pre-loop: stage chunks 0..2 of step 0
  stage(0); stage(1); stage(2);

  // ---- time loop ----
  #pragma unroll 1
  for (int t = 0; t < T; ++t){
    const int pb = t & 1;
    const u16* hs_hi = hb_hi + pb * (Bsz * Hn);
    const u16* hs_lo = hb_lo + pb * (Bsz * Hn);
    u16* hd_hi = hb_hi + (pb ^ 1) * (Bsz * Hn);
    u16* hd_lo = hb_lo + (pb ^ 1) * (Bsz * Hn);

    f32x4 acc[4];
    #pragma unroll
    for (int nt = 0; nt < 4; ++nt)
      #pragma unroll
      for (int e = 0; e < 4; ++e)
        acc[nt][e] = bias_r[nt];
    if (t == 0){
      #pragma unroll
      for (int e = 0; e < 4; ++e){
        const float yi = yinit[wrow0 + q * 4 + e];
        #pragma unroll
        for (int nt = 0; nt < 4; ++nt)
          acc[nt][e] -= yi * wih_r[nt];
      }
    }

    const volatile u16* ha_hi = hs_hi + (size_t)(wrow0 + r) * Hn + q * 8;
    const volatile u16* ha_lo = hs_lo + (size_t)(wrow0 + r) * Hn + q * 8;

    // depth-3 h register ring (4 slots): HLOAD(c) = 4 volatile VMEM loads
    bf16x8 hh[4][2], hl[4][2];
    #define HLOAD(cc) {                                       \
      const int s_ = (cc) & 3;                                \
      hh[s_][0] = vld8(ha_hi + (cc) * 64);                    \
      hl[s_][0] = vld8(ha_lo + (cc) * 64);                    \
      hh[s_][1] = vld8(ha_hi + (cc) * 64 + 32);               \
      hl[s_][1] = vld8(ha_lo + (cc) * 64 + 32);               }

    HLOAD(0); HLOAD(1); HLOAD(2);   // h prologue (12 loads)

    #pragma unroll
    for (int c = 0; c < 16; ++c){
      // stage(c) & h(c) guaranteed complete: 16 newer VMEM ops allowed outstanding
      if (c < 15) asm volatile("s_waitcnt vmcnt(16)" ::: "memory");
      else        asm volatile("s_waitcnt vmcnt(0)"  ::: "memory");
      __builtin_amdgcn_s_barrier();
      asm volatile("" ::: "memory");   // fence: no LDS reads hoisted above barrier

      const int buf = c & 3;
      #pragma unroll
      for (int kc = 0; kc < 2; ++kc){
        const bf16x8 ah = hh[buf][kc];
        const bf16x8 al = hl[buf][kc];
        #pragma unroll
        for (int nt = 0; nt < 4; ++nt){
          const int cc = jt * 64 + nt * 16 + r;
          const int sl = ((kc * 4 + q) ^ (cc & 7)) * 8;
          const bf16x8 bh = ld8(&ldsB[buf][0][cc * 64 + sl]);
          const bf16x8 bl = ld8(&ldsB[buf][1][cc * 64 + sl]);
          acc[nt] = __builtin_amdgcn_mfma_f32_16x16x32_bf16(ah, bh, acc[nt], 0, 0, 0);
          acc[nt] = __builtin_amdgcn_mfma_f32_16x16x32_bf16(ah, bl, acc[nt], 0, 0, 0);
          acc[nt] = __builtin_amdgcn_mfma_f32_16x16x32_bf16(al, bh, acc[nt], 0, 0, 0);
        }
      }

      // issue next h + stage AFTER this barrier (buffer (c+3)&3 was last read at c-1)
      if (c < 13){
        HLOAD(c + 3);
        stage(c + 3);
      }
    }
    #undef HLOAD

    // ---- pointwise LSTM cell: all 4 gates lane-local (nt = gate) ----
    float pp[4];
    #pragma unroll
    for (int e = 0; e < 4; ++e){
      const float gi = sigm(acc[0][e]);
      const float gf = sigm(acc[1][e]);
      const float gg = tanh_f(acc[2][e]);
      const float go = sigm(acc[3][e]);
      const float cn = gf * creg[e] + gi * gg;
      creg[e] = cn;
      const float hn = go * tanh_f(cn);
      const int row = wrow0 + q * 4 + e;
      const u16 hi = f2bf(hn);
      hd_hi[(size_t)row * Hn + j] = hi;
      hd_lo[(size_t)row * Hn + j] = f2bf(hn - bf2f(hi));
      pp[e] = hn * wout_r;
    }
    #pragma unroll
    for (int m = 1; m < 16; m <<= 1)
      #pragma unroll
      for (int e = 0; e < 4; ++e)
        pp[e] += __shfl_xor(pp[e], m, 64);
    if (r == 0){
      #pragma unroll
      for (int e = 0; e < 4; ++e){
        const int row_l = rowg * 16 + q * 4 + e;
        ypart[((size_t)(pb * 8 + xcd) * 64 + row_l) * 64 + slot * 2 + jt] = pp[e];
      }
    }

    // ---- XCD-local barrier: no fences (same-L2 coherence) ----
    __syncthreads();                 // drains all waves' h/ypart stores to L2
    if (tid == 0) *myflag = (u32)(t + 1);
    if (t < T - 1){ stage(0); stage(1); stage(2); }  // next step's chunks (W immutable)

    if (w == 0){
      const u32 tgt = (u32)(t + 1);
      for (int spin = 0; spin < (1 << 17); ++spin){
        const u32 f = (lane < 32) ? gflag[(size_t)lane * 16] : tgt;
        if (__all(f >= tgt)) break;
        __builtin_amdgcn_s_sleep(1);
      }
    }
    __syncthreads();                 // also drains the 3 pre-staged chunks

    // ---- y output for step t: each block reduces its 2 rows (XCD-local reads) ----
    if (tid < 64){
      const int rsel = lane >> 5, ll = lane & 31;
      const int row_l = slot * 2 + rsel;
      const volatile float* yp = ypart + ((size_t)(pb * 8 + xcd) * 64 + row_l) * 64;
      float v = yp[ll] + yp[ll + 32];
      #pragma unroll
      for (int m = 1; m < 32; m <<= 1) v += __shfl_xor(v, m, 64);
      if (ll == 0) outp[(size_t)(row0x + row_l) * T + t] = v + bo;
    }
  }
}

extern "C" void kernel_launch(void* const* d_in, const int* in_sizes, int n_in,
                              void* d_out, int out_size, void* d_ws, size_t ws_size,
                              hipStream_t stream)
{
  const float* z    = (const float*)d_in[0];
  const float* Wzh  = (const float*)d_in[1];
  const float* bzh  = (const float*)d_in[2];
  const float* Wzc  = (const float*)d_in[3];
  const float* bzc  = (const float*)d_in[4];
  const float* Wih  = (const float*)d_in[5];
  const float* Whh  = (const float*)d_in[6];
  const float* b_ih = (const float*)d_in[7];
  const float* b_hh = (const float*)d_in[8];
  const float* Wout = (const float*)d_in[9];
  const float* bout = (const float*)d_in[10];
  const int*   tlen = (const int*)d_in[11];
  float* outp = (float*)d_out;

  char* ws = (char*)d_ws;
  size_t off = 0;
  auto alloc = [&](size_t bytes) -> char* {
    char* p = ws + off;
    off += (bytes + 255) & ~size_t(255);
    return p;
  };
  u16* wp_hi  = (u16*)alloc((size_t)G4H * Hn * 2);
  u16* wp_lo  = (u16*)alloc((size_t)G4H * Hn * 2);
  u16* hb_hi  = (u16*)alloc((size_t)2 * Bsz * Hn * 2);
  u16* hb_lo  = (u16*)alloc((size_t)2 * Bsz * Hn * 2);
  float* cbuf    = (float*)alloc((size_t)Bsz * Hn * 4);
  float* yinit   = (float*)alloc((size_t)Bsz * 4);
  float* bpack   = (float*)alloc((size_t)G4H * 4);
  float* wihpack = (float*)alloc((size_t)G4H * 4);
  float* ypart   = (float*)alloc((size_t)2 * 8 * 64 * 64 * 4);
  u32* claim     = (u32*)alloc(8 * 16 * 4);            // 64B-padded per-XCD counters
  u32* flags     = (u32*)alloc((size_t)8 * 32 * 16 * 4);

  (void)hipMemsetAsync(claim, 0, 8 * 16 * 4, stream);
  (void)hipMemsetAsync(flags, 0, (size_t)8 * 32 * 16 * 4, stream);

  repack_kernel<<<dim3(1024), dim3(256), 0, stream>>>(
      Whh, b_ih, b_hh, Wih, Wout, bout, wp_hi, wp_lo, bpack, wihpack);

  init_kernel<<<dim3(Bsz), dim3(256), 0, stream>>>(
      z, Wzh, bzh, Wzc, bzc, Wout, bout, hb_hi, hb_lo, cbuf, yinit);

  lstm_xcd<<<dim3(NBLK), dim3(512), 0, stream>>>(
      wp_hi, wp_lo, bpack, wihpack, Wout, bout, yinit,
      hb_hi, hb_lo, cbuf, ypart, outp, tlen, claim, flags);
}

// Round 14
// 6859.893 us; speedup vs baseline: 1.3819x; 1.3819x over previous
//
#include <hip/hip_runtime.h>

typedef unsigned short u16;
typedef unsigned int u32;
typedef __bf16 bf16x8 __attribute__((ext_vector_type(8)));
typedef float f32x4 __attribute__((ext_vector_type(4)));
typedef u16 u16x8 __attribute__((ext_vector_type(8)));

#define AS1 __attribute__((address_space(1)))
#define AS3 __attribute__((address_space(3)))

constexpr int Bsz = 512;   // batch
constexpr int LATn = 128;  // latent
constexpr int Hn  = 1024;  // hidden
constexpr int G4H = 4096;  // 4*H
constexpr int NBLK = 256;

__device__ __forceinline__ u16 f2bf(float x){
  u32 u = __float_as_uint(x);
  return (u16)((u + 0x7FFFu + ((u >> 16) & 1u)) >> 16);
}
__device__ __forceinline__ float bf2f(u16 h){ return __uint_as_float(((u32)h) << 16); }

__device__ __forceinline__ float sigm(float x){
  float e = __builtin_amdgcn_exp2f(x * -1.44269504088896f);
  return __builtin_amdgcn_rcpf(1.0f + e);
}
__device__ __forceinline__ float tanh_f(float x){
  float e = __builtin_amdgcn_exp2f(x * -2.88539008177793f);
  return __builtin_amdgcn_rcpf(1.0f + e) * 2.0f - 1.0f;
}

__device__ __forceinline__ bf16x8 ld8(const u16* p){
  u16x8 v = *reinterpret_cast<const u16x8*>(p);
  return __builtin_bit_cast(bf16x8, v);
}
// volatile load: bypass L1 so same-XCD L2 (the coherence point) is always consulted
__device__ __forceinline__ bf16x8 vld8(const volatile u16* p){
  u16x8 v = *reinterpret_cast<const volatile u16x8*>(p);
  return __builtin_bit_cast(bf16x8, v);
}

__device__ __forceinline__ void load16_lds(const u16* g, u16* l){
  __builtin_amdgcn_global_load_lds((AS1 void*)(u16*)g, (AS3 void*)l, 16, 0, 0);
}

// ---------------- repack: fold y-feedback into weights, fp32 -> SINGLE bf16 ----------------
// W'[gc][k] = Whh[gc][k] + Wout[k]*Wih[gc];  bias' = b_ih + b_hh + bo*Wih
// 64-col gate packing (all 4 gates of 16 j's contiguous): drow = (jj>>4)*64 + g*16 + (jj&15)
__global__ void repack_kernel(
    const float* __restrict__ Whh, const float* __restrict__ b_ih, const float* __restrict__ b_hh,
    const float* __restrict__ Wih, const float* __restrict__ Wout, const float* __restrict__ bout,
    u16* wp, float* bpack, float* wihpack)
{
  const int idx0 = blockIdx.x * blockDim.x + threadIdx.x;
  const int stride = gridDim.x * blockDim.x;
  const float bo = bout[0];
  for (int i = idx0; i < G4H * Hn; i += stride){
    int row = i >> 10, k = i & 1023;
    int g = row >> 10, jj = row & 1023;
    int drow = (jj >> 4) * 64 + g * 16 + (jj & 15);
    float x = Whh[i] + Wout[k] * Wih[row];
    wp[drow * 1024 + k] = f2bf(x);
  }
  for (int i = idx0; i < G4H; i += stride){
    int g = i >> 10, jj = i & 1023;
    int drow = (jj >> 4) * 64 + g * 16 + (jj & 15);
    bpack[drow] = b_ih[i] + b_hh[i] + bo * Wih[i];
    wihpack[drow] = Wih[i];
  }
}

// ---------------- init: h0, c0, y_init (one block per batch row) ----------------
__global__ __launch_bounds__(256, 1) void init_kernel(
    const float* __restrict__ z,
    const float* __restrict__ Wzh, const float* __restrict__ bzh,
    const float* __restrict__ Wzc, const float* __restrict__ bzc,
    const float* __restrict__ Wout, const float* __restrict__ bout,
    u16* hb_hi, u16* hb_lo, float* cbuf, float* yinit)
{
  __shared__ float zrow[LATn];
  __shared__ float yred[256];
  const int b = blockIdx.x, tid = threadIdx.x;
  if (tid < LATn) zrow[tid] = z[b * LATn + tid];
  __syncthreads();
  float ysum = 0.f;
  #pragma unroll
  for (int jj = 0; jj < 4; ++jj){
    const int j = tid * 4 + jj;
    const float* wh = Wzh + (size_t)j * LATn;
    const float* wc = Wzc + (size_t)j * LATn;
    float sh = bzh[j], sc = bzc[j];
    for (int k = 0; k < LATn; ++k){
      const float zv = zrow[k];
      sh = fmaf(zv, wh[k], sh);
      sc = fmaf(zv, wc[k], sc);
    }
    const float h0 = tanh_f(sh);
    cbuf[(size_t)b * Hn + j] = tanh_f(sc);
    const u16 hi = f2bf(h0);
    hb_hi[(size_t)b * Hn + j] = hi;
    hb_lo[(size_t)b * Hn + j] = f2bf(h0 - bf2f(hi));
    ysum = fmaf(h0, Wout[j], ysum);
  }
  yred[tid] = ysum;
  __syncthreads();
  for (int s = 128; s > 0; s >>= 1){
    if (tid < s) yred[tid] += yred[tid + s];
    __syncthreads();
  }
  if (tid == 0) yinit[b] = yred[0] + bout[0];
}

// ---------------- persistent XCD-local LSTM kernel, single-bf16 W' stream ----------------
// 256 blocks x 512 threads, 128 KB LDS ring (4 x 32 KB chunks) -> 1 block/CU -> 32/XCD.
// XCD x owns batch rows [x*64, x*64+64): no fences, XCD-local flag barrier.
// W' (single bf16, 8.4 MB) streamed L3 -> LDS in 8 chunks/step of 128 k-cols each,
// ring-4, 3 chunks in flight, exact counted vmcnt per chunk. h read inline from L2.
__global__ __launch_bounds__(512, 1) void lstm_xcd(
    const u16* __restrict__ wp,
    const float* __restrict__ bpack, const float* __restrict__ wihpack,
    const float* __restrict__ Wout, const float* __restrict__ bout,
    const float* __restrict__ yinit,
    u16* __restrict__ hb_hi, u16* __restrict__ hb_lo,
    const float* __restrict__ cbuf, float* __restrict__ ypart,
    float* __restrict__ outp, const int* __restrict__ tlen,
    u32* claim, volatile u32* flags)
{
  __shared__ __align__(16) u16 ldsB[4][16384];  // 128 KiB ring: [buf][col*16 + sp][8]
  __shared__ int sh_ids[2];

  const int tid = threadIdx.x;
  const int lane = tid & 63, w = tid >> 6;
  const int r = lane & 15, q = lane >> 4;
  const int rowg = w >> 1, jt = w & 1;
  const int T = tlen[0];

  // ---- physical XCD id + slot claim ----
  if (tid == 0){
    const int xcd_ = (int)(__builtin_amdgcn_s_getreg(6164) & 7);  // HW_REG_XCC_ID(20), sz 4
    const int slot_ = (int)atomicAdd(&claim[xcd_ * 16], 1u);
    sh_ids[0] = xcd_; sh_ids[1] = slot_;
  }
  __syncthreads();
  const int xcd = sh_ids[0];
  const int slot = sh_ids[1] & 31;

  const int jcol0 = slot * 128;                 // packed W' col base (128 cols = 32 j)
  const int j = slot * 32 + jt * 16 + r;        // this lane's hidden unit
  const int row0x = xcd * 64;                   // XCD's batch-row base
  const int wrow0 = row0x + rowg * 16;          // wave's A-row base

  volatile u32* myflag = flags + (size_t)(xcd * 32 + slot) * 16;  // 64B padded
  volatile u32* gflag  = flags + (size_t)(xcd * 32) * 16;

  // per-lane constants
  float bias_r[4], wih_r[4];
  #pragma unroll
  for (int nt = 0; nt < 4; ++nt){
    bias_r[nt] = bpack[jcol0 + jt * 64 + nt * 16 + r];
    wih_r[nt]  = wihpack[jcol0 + jt * 64 + nt * 16 + r];
  }
  const float wout_r = Wout[j];
  const float bo = bout[0];

  // c state in registers for all steps: rows q*4+e of this wave, column j
  float creg[4];
  #pragma unroll
  for (int e = 0; e < 4; ++e)
    creg[e] = cbuf[(size_t)(wrow0 + q * 4 + e) * Hn + j];

  const u16* wph = wp + (size_t)jcol0 * 1024;

  // stage W' chunk c (128 cols x 128 k = 32 KB) into ldsB[c&3]; 4 loads/thread
  auto stage = [&](int c){
    const int buf = c & 3;
    #pragma unroll
    for (int i = 0; i < 4; ++i){
      const int idx = i * 512 + tid;
      const int col = idx >> 4, sp = idx & 15;
      const int sgk = (sp ^ (col & 7)) * 8;     // inverse of read-side swizzle
      const int dst = (i * 512 + w * 64) * 8;   // wave-uniform; HW adds lane*16B
      load16_lds(wph + (size_t)col * 1024 + c * 128 + sgk, &ldsB[buf][dst]);
    }
  };

  // pre-loop: stage chunks 0..2 of step 0
  stage(0); stage(1); stage(2);

  // ---- time loop ----
  #pragma unroll 1
  for (int t = 0; t < T; ++t){
    const int pb = t & 1;
    const u16* hs_hi = hb_hi + pb * (Bsz * Hn);
    const u16* hs_lo = hb_lo + pb * (Bsz * Hn);
    u16* hd_hi = hb_hi + (pb ^ 1) * (Bsz * Hn);
    u16* hd_lo = hb_lo + (pb ^ 1) * (Bsz * Hn);

    f32x4 acc[4];
    #pragma unroll
    for (int nt = 0; nt < 4; ++nt)
      #pragma unroll
      for (int e = 0; e < 4; ++e)
        acc[nt][e] = bias_r[nt];
    if (t == 0){
      #pragma unroll
      for (int e = 0; e < 4; ++e){
        const float yi = yinit[wrow0 + q * 4 + e];
        #pragma unroll
        for (int nt = 0; nt < 4; ++nt)
          acc[nt][e] -= yi * wih_r[nt];
      }
    }

    const volatile u16* ha_hi = hs_hi + (size_t)(wrow0 + r) * Hn + q * 8;
    const volatile u16* ha_lo = hs_lo + (size_t)(wrow0 + r) * Hn + q * 8;

    #pragma unroll
    for (int c = 0; c < 8; ++c){
      // exact counted waits: stage(c) complete; newer prefetches stay in flight
      if (c == 0)      asm volatile("s_waitcnt vmcnt(8)"  ::: "memory");
      else if (c == 1) asm volatile("s_waitcnt vmcnt(16)" ::: "memory");
      else if (c == 2) asm volatile("s_waitcnt vmcnt(24)" ::: "memory");
      else if (c <= 5) asm volatile("s_waitcnt vmcnt(32)" ::: "memory");
      else if (c == 6) asm volatile("s_waitcnt vmcnt(28)" ::: "memory");
      else             asm volatile("s_waitcnt vmcnt(24)" ::: "memory");
      __builtin_amdgcn_s_barrier();
      asm volatile("" ::: "memory");   // no LDS reads hoisted above barrier

      if (c < 5) stage(c + 3);         // buf (c+3)&3 last read at chunk c-1

      const int buf = c & 3;
      #pragma unroll
      for (int kc = 0; kc < 4; ++kc){
        const int ko = c * 128 + kc * 32;
        const bf16x8 ah = vld8(ha_hi + ko);
        const bf16x8 al = vld8(ha_lo + ko);
        #pragma unroll
        for (int nt = 0; nt < 4; ++nt){
          const int cc = jt * 64 + nt * 16 + r;
          const int phys = (kc * 4 + q) ^ (cc & 7);
          const bf16x8 bh = ld8(&ldsB[buf][(cc * 16 + phys) * 8]);
          acc[nt] = __builtin_amdgcn_mfma_f32_16x16x32_bf16(ah, bh, acc[nt], 0, 0, 0);
          acc[nt] = __builtin_amdgcn_mfma_f32_16x16x32_bf16(al, bh, acc[nt], 0, 0, 0);
        }
      }
    }

    // ---- pointwise LSTM cell: all 4 gates lane-local (nt = gate) ----
    float pp[4];
    #pragma unroll
    for (int e = 0; e < 4; ++e){
      const float gi = sigm(acc[0][e]);
      const float gf = sigm(acc[1][e]);
      const float gg = tanh_f(acc[2][e]);
      const float go = sigm(acc[3][e]);
      const float cn = gf * creg[e] + gi * gg;
      creg[e] = cn;
      const float hn = go * tanh_f(cn);
      const int row = wrow0 + q * 4 + e;
      const u16 hi = f2bf(hn);
      hd_hi[(size_t)row * Hn + j] = hi;
      hd_lo[(size_t)row * Hn + j] = f2bf(hn - bf2f(hi));
      pp[e] = hn * wout_r;
    }
    #pragma unroll
    for (int m = 1; m < 16; m <<= 1)
      #pragma unroll
      for (int e = 0; e < 4; ++e)
        pp[e] += __shfl_xor(pp[e], m, 64);
    if (r == 0){
      #pragma unroll
      for (int e = 0; e < 4; ++e){
        const int row_l = rowg * 16 + q * 4 + e;
        ypart[((size_t)(pb * 8 + xcd) * 64 + row_l) * 64 + slot * 2 + jt] = pp[e];
      }
    }

    // ---- XCD-local barrier: no fences (same-L2 coherence) ----
    __syncthreads();                 // drains all waves' h/ypart stores to L2
    if (tid == 0) *myflag = (u32)(t + 1);
    if (t < T - 1){ stage(0); stage(1); stage(2); }  // next step's chunks (W immutable)

    if (w == 0){
      const u32 tgt = (u32)(t + 1);
      for (int spin = 0; spin < (1 << 17); ++spin){
        const u32 f = (lane < 32) ? gflag[(size_t)lane * 16] : tgt;
        if (__all(f >= tgt)) break;
        __builtin_amdgcn_s_sleep(1);
      }
    }
    __syncthreads();                 // also drains the 3 pre-staged chunks

    // ---- y output for step t: each block reduces its 2 rows (XCD-local reads) ----
    if (tid < 64){
      const int rsel = lane >> 5, ll = lane & 31;
      const int row_l = slot * 2 + rsel;
      const volatile float* yp = ypart + ((size_t)(pb * 8 + xcd) * 64 + row_l) * 64;
      float v = yp[ll] + yp[ll + 32];
      #pragma unroll
      for (int m = 1; m < 32; m <<= 1) v += __shfl_xor(v, m, 64);
      if (ll == 0) outp[(size_t)(row0x + row_l) * T + t] = v + bo;
    }
  }
}

extern "C" void kernel_launch(void* const* d_in, const int* in_sizes, int n_in,
                              void* d_out, int out_size, void* d_ws, size_t ws_size,
                              hipStream_t stream)
{
  const float* z    = (const float*)d_in[0];
  const float* Wzh  = (const float*)d_in[1];
  const float* bzh  = (const float*)d_in[2];
  const float* Wzc  = (const float*)d_in[3];
  const float* bzc  = (const float*)d_in[4];
  const float* Wih  = (const float*)d_in[5];
  const float* Whh  = (const float*)d_in[6];
  const float* b_ih = (const float*)d_in[7];
  const float* b_hh = (const float*)d_in[8];
  const float* Wout = (const float*)d_in[9];
  const float* bout = (const float*)d_in[10];
  const int*   tlen = (const int*)d_in[11];
  float* outp = (float*)d_out;

  char* ws = (char*)d_ws;
  size_t off = 0;
  auto alloc = [&](size_t bytes) -> char* {
    char* p = ws + off;
    off += (bytes + 255) & ~size_t(255);
    return p;
  };
  u16* wp     = (u16*)alloc((size_t)G4H * Hn * 2);
  u16* hb_hi  = (u16*)alloc((size_t)2 * Bsz * Hn * 2);
  u16* hb_lo  = (u16*)alloc((size_t)2 * Bsz * Hn * 2);
  float* cbuf    = (float*)alloc((size_t)Bsz * Hn * 4);
  float* yinit   = (float*)alloc((size_t)Bsz * 4);
  float* bpack   = (float*)alloc((size_t)G4H * 4);
  float* wihpack = (float*)alloc((size_t)G4H * 4);
  float* ypart   = (float*)alloc((size_t)2 * 8 * 64 * 64 * 4);
  u32* claim     = (u32*)alloc(8 * 16 * 4);            // 64B-padded per-XCD counters
  u32* flags     = (u32*)alloc((size_t)8 * 32 * 16 * 4);

  (void)hipMemsetAsync(claim, 0, 8 * 16 * 4, stream);
  (void)hipMemsetAsync(flags, 0, (size_t)8 * 32 * 16 * 4, stream);

  repack_kernel<<<dim3(1024), dim3(256), 0, stream>>>(
      Whh, b_ih, b_hh, Wih, Wout, bout, wp, bpack, wihpack);

  init_kernel<<<dim3(Bsz), dim3(256), 0, stream>>>(
      z, Wzh, bzh, Wzc, bzc, Wout, bout, hb_hi, hb_lo, cbuf, yinit);

  lstm_xcd<<<dim3(NBLK), dim3(512), 0, stream>>>(
      wp, bpack, wihpack, Wout, bout, yinit,
      hb_hi, hb_lo, cbuf, ypart, outp, tlen, claim, flags);
}